// Round 2
// baseline (105.410 us; speedup 1.0000x reference)
//
#include <hip/hip_runtime.h>
#include <math.h>

#define BS 2
#define C  32
#define H  256
#define W  256
#define HW (H * W)
#define PS 5

// f32(pi), matching JAX's rounding of np.pi to float32
#define PI_F 3.14159274101257324e+00f

// ws layout: lo plane (BS,HW,16) floats, then hi plane (BS,HW,16) floats.
#define HALF_FLOATS (BS * HW * 16)

// ---------------------------------------------------------------------------
// Kernel 1: transpose source (b, c, h, w) -> two half-planes (b, h*w, 16).
// Each gather point then reads one contiguous 64B row from ONE half-plane,
// and one (b, half) plane = 4.19 MB = fits a single XCD's 4 MiB L2.
// Conflict-free LDS (2-way max = free), coalesced global both sides.
// ---------------------------------------------------------------------------
__global__ __launch_bounds__(256) void transpose_split(
    const float* __restrict__ src, float* __restrict__ ws) {
    __shared__ float lds[C][64 + 1];   // bank = (ch+px)%32 -> 2-way max (free)

    const int block = blockIdx.x;                  // BS * HW/64 = 2048 blocks
    const int b     = block / (HW / 64);
    const int p0    = (block % (HW / 64)) * 64;    // 64 consecutive pixels
    const int tid   = threadIdx.x;
    const int px    = tid & 63;
    const int g     = tid >> 6;                    // wave id 0..3

    const float* sb = src + (size_t)b * C * HW;
    #pragma unroll
    for (int k = 0; k < 8; ++k) {
        const int ch = k * 4 + g;                  // covers 0..31
        lds[ch][px] = sb[(size_t)ch * HW + p0 + px];   // 256B coalesced / wave
    }
    __syncthreads();

    float* lo = ws + ((size_t)b * HW + p0) * 16;
    float* hi = ws + HALF_FLOATS + ((size_t)b * HW + p0) * 16;
    #pragma unroll
    for (int k = 0; k < 8; ++k) {
        const int e  = k * 256 + tid;              // 0..2047
        const int pl = e >> 5;                     // pixel within tile
        const int ch = e & 31;                     // channel
        const int c  = ch & 15;
        const float v = lds[ch][pl];               // 2-way max (free)
        if (ch < 16) lo[pl * 16 + c] = v;          // 2x contiguous 128B/instr
        else         hi[pl * 16 + c] = v;
    }
}

// ---------------------------------------------------------------------------
// Kernel 2: gather + 5x5 patch sum, XCD-pinned.
// blockIdx&7 ~ XCD (round-robin dispatch heuristic). Each XCD serves exactly
// one (batch, half) combo -> its random-gather working set is one 4.19 MB
// half-plane, L2-resident. 4 lanes/pixel, one float4 each: every 64B row
// fully consumed, zero over-fetch.
// ---------------------------------------------------------------------------
__global__ __launch_bounds__(256) void gather_sum_half(
    const float* __restrict__ ws,     // half-planes
    const float* __restrict__ nnf,    // (b, 3, h, w)
    float* __restrict__ out) {        // (b, c, h, w)
    const unsigned blk   = blockIdx.x;         // 4096 blocks
    const unsigned xcd   = blk & 7u;
    const unsigned combo = xcd >> 1;           // 0..3
    const unsigned b     = combo >> 1;         // batch
    const unsigned half  = combo & 1u;         // channel half
    const unsigned tile  = (xcd & 1u) * 512u + (blk >> 3);   // 0..1023
    const unsigned tid   = threadIdx.x;
    const unsigned px    = tid >> 2;           // 0..63
    const unsigned k     = tid & 3u;           // float4 within 64B row
    const unsigned p     = tile * 64u + px;    // pixel 0..65535

    const float* nb = nnf + (size_t)b * 3 * HW;
    const float ci = nb[p];                    // row coord
    const float cj = nb[HW + p];               // col coord
    const float a  = nb[2 * HW + p];           // angle in [0,1)

    // Match XLA: sin(a*pi_f32)/cos via ocml; block FMA contraction everywhere
    const float arg = __fmul_rn(a, PI_F);
    const float s = sinf(arg);
    const float c = cosf(arg);

    const float4* tb = (const float4*)(ws + (size_t)half * HALF_FLOATS
                                          + (size_t)b * HW * 16) + k;

    float4 acc = make_float4(0.f, 0.f, 0.f, 0.f);
    #pragma unroll
    for (int i = 0; i < PS; ++i) {
        #pragma unroll
        for (int j = 0; j < PS; ++j) {
            const float fi = (float)(i - 2);       // pi_j = xx = i-2
            const float fj = (float)(j - 2);       // pi_i = yy = j-2
            // iR = (j-2)*s - (i-2)*c ; jR = (j-2)*c - (i-2)*s  (no contraction)
            const float iR = __fsub_rn(__fmul_rn(fj, s), __fmul_rn(fi, c));
            const float jR = __fsub_rn(__fmul_rn(fj, c), __fmul_rn(fi, s));
            float pr = __fadd_rn(ci, iR);
            float pc = __fadd_rn(cj, jR);
            pr = fminf(fmaxf(pr, 0.0f), (float)(H - 1));
            pc = fminf(fmaxf(pc, 0.0f), (float)(W - 1));
            const int row = (int)pr;               // trunc == floor (>=0)
            const int col = (int)pc;
            const int idx = (row << 8) + col;
            const float4 v = tb[idx * 4];          // 64B row, 4 lanes cover it
            acc.x += v.x; acc.y += v.y; acc.z += v.z; acc.w += v.w;
        }
    }

    float* ob = out + ((size_t)b * C + half * 16 + k * 4) * HW + p;
    ob[0]              = acc.x;
    ob[HW]             = acc.y;
    ob[2 * (size_t)HW] = acc.z;
    ob[3 * (size_t)HW] = acc.w;
}

extern "C" void kernel_launch(void* const* d_in, const int* in_sizes, int n_in,
                              void* d_out, int out_size, void* d_ws, size_t ws_size,
                              hipStream_t stream) {
    const float* src = (const float*)d_in[0];   // (2, 32, 256, 256) f32
    const float* nnf = (const float*)d_in[1];   // (2, 3, 256, 256) f32
    float* out = (float*)d_out;                 // (2, 32, 256, 256) f32
    float* ws  = (float*)d_ws;                  // needs 16.8 MB

    transpose_split<<<BS * (HW / 64), 256, 0, stream>>>(src, ws);
    gather_sum_half<<<4096, 256, 0, stream>>>(ws, nnf, out);
}